// Round 8
// baseline (135.414 us; speedup 1.0000x reference)
//
#include <hip/hip_runtime.h>
#include <hip/hip_fp16.h>

typedef _Float16 f16;
typedef __attribute__((ext_vector_type(8))) _Float16 half8;
typedef __attribute__((ext_vector_type(2))) __fp16 fp16x2_native;
typedef __attribute__((ext_vector_type(4))) float floatx4;
typedef __attribute__((ext_vector_type(16))) float f32x16;
typedef __attribute__((ext_vector_type(4))) unsigned uint4v;
typedef __attribute__((ext_vector_type(2))) unsigned uint2v;

static constexpr int DIM = 1024;
static constexpr int SEQ = 2048;
static constexpr int DH = 64;
static constexpr int MTOT = 4096;  // BATCH * SEQ
static constexpr int QTOT = 65536; // 32 bh * 2048 q

__device__ __forceinline__ float fexp2(float x) {
#if __has_builtin(__builtin_amdgcn_exp2f)
  return __builtin_amdgcn_exp2f(x);
#else
  return exp2f(x);
#endif
}

__device__ __forceinline__ unsigned pkrtz(float a, float b) {
  fp16x2_native h = __builtin_amdgcn_cvt_pkrtz(a, b);
  return __builtin_bit_cast(unsigned, h);
}

__device__ __forceinline__ void pl32swap(unsigned& a, unsigned& b) {
#if __has_builtin(__builtin_amdgcn_permlane32_swap)
  uint2v r = __builtin_amdgcn_permlane32_swap(a, b, false, false);
  a = r.x;
  b = r.y;
#else
  asm volatile("v_permlane32_swap_b32 %0, %1" : "+v"(a), "+v"(b));
#endif
}

// async global->LDS 16B
__device__ __forceinline__ void gll16(const f16* g, f16* l) {
  auto gp = (__attribute__((address_space(1))) unsigned*)(uintptr_t)(const void*)g;
  auto lp = (__attribute__((address_space(3))) unsigned*)(uintptr_t)(void*)l;
  __builtin_amdgcn_global_load_lds(gp, lp, 16, 0, 0);
}

// ---- weight transpose + fp16 convert: wt[z][n][k] = W_z[k][n] ----
__global__ __launch_bounds__(256) void k_transpose(
    const float* __restrict__ Wq, const float* __restrict__ Wk,
    const float* __restrict__ Wv, const float* __restrict__ Wo,
    f16* __restrict__ wt)
{
  __shared__ float tile[32][33];
  const int z = blockIdx.z;
  const float* W = (z == 0) ? Wq : (z == 1) ? Wk : (z == 2) ? Wv : Wo;
  f16* out = wt + (size_t)z * DIM * DIM;
  const int tx = threadIdx.x, ty = threadIdx.y;
  const int x0 = blockIdx.x * 32, y0 = blockIdx.y * 32;
#pragma unroll
  for (int i = 0; i < 4; ++i)
    tile[ty + i * 8][tx] = W[(size_t)(y0 + ty + i * 8) * DIM + (x0 + tx)];
  __syncthreads();
#pragma unroll
  for (int i = 0; i < 4; ++i)
    out[(size_t)(x0 + ty + i * 8) * DIM + (y0 + tx)] = (f16)tile[tx][ty + i * 8];
}

// ---- x fp32 -> fp16 ----
__global__ __launch_bounds__(256) void k_xcast(
    const float* __restrict__ in, f16* __restrict__ out)
{
  const int i = blockIdx.x * 256 + threadIdx.x;
  const float4* p = (const float4*)in;
  float4 a = p[2 * i], b = p[2 * i + 1];
  half8 h = {(f16)a.x, (f16)a.y, (f16)a.z, (f16)a.w,
             (f16)b.x, (f16)b.y, (f16)b.z, (f16)b.w};
  *(half8*)(out + (size_t)i * 8) = h;
}

// ---- V^T pre-transpose: vt[bh][d][n] = V[b][n][h*64+d] ----
__global__ __launch_bounds__(256) void k_vtrans(
    const f16* __restrict__ vh, f16* __restrict__ vt)
{
  __shared__ f16 T[64][72];
  const int tid = threadIdx.x;
  const int nt = blockIdx.x, bh = blockIdx.y;
  const int b = bh >> 4, h = bh & 15;
  const int n0 = nt * 64;
  const f16* src = vh + (size_t)b * SEQ * DIM + (size_t)h * DH;
#pragma unroll
  for (int i = 0; i < 2; ++i) {
    const int n = (tid >> 3) + i * 32;
    const int cc = tid & 7;
    half8 v = *(const half8*)(src + (size_t)(n0 + n) * DIM + cc * 8);
#pragma unroll
    for (int j = 0; j < 8; ++j) T[cc * 8 + j][n] = v[j];
  }
  __syncthreads();
  f16* dst = vt + (size_t)bh * DH * SEQ;
#pragma unroll
  for (int i = 0; i < 2; ++i) {
    const int d = (tid >> 3) + i * 32;
    const int cc = tid & 7;
    half8 w = *(const half8*)&T[d][cc * 8];
    *(half8*)(dst + (size_t)d * SEQ + n0 + cc * 8) = w;
  }
}

// ---- fp16 GEMM, 128x128 tile, BK=32, gll double-buffer, 1 barrier/step ----
// A_HM: A stored head-major [bh][n][64] (bh = b*16+h), logical A[m][k]=A[b*2048+n][h*64+kd]
template <bool OUT_F32, bool A_HM>
__global__ __launch_bounds__(256) void k_gemm2(
    const f16* __restrict__ A, const f16* __restrict__ BT,
    void* __restrict__ Cptr, const float* __restrict__ bias,
    int M, int N, int K, size_t bt_zstride, size_t c_zstride)
{
  __shared__ f16 SB[2][8192];

  const int tid = threadIdx.x;
  const int lane = tid & 63;
  const int wid = tid >> 6;
  const int wr = (wid >> 1) * 64, wc = (wid & 1) * 64;
  const int li = lane & 15, lg = lane >> 4;

  const f16* BTz = BT + (size_t)blockIdx.z * bt_zstride;
  const int row0 = blockIdx.x * 128, col0 = blockIdx.y * 128;

  const int c0 = tid;
  const int c1 = 256 + tid;
  const f16* a0;
  const f16* a1;
  if constexpr (A_HM) {
    const int m0 = row0 + (c0 >> 2), m1 = row0 + (c1 >> 2);
    a0 = A + (size_t)(m0 >> 11) * 16 * 131072 + (size_t)(m0 & 2047) * 64 + (c0 & 3) * 8;
    a1 = A + (size_t)(m1 >> 11) * 16 * 131072 + (size_t)(m1 & 2047) * 64 + (c1 & 3) * 8;
  } else {
    a0 = A + (size_t)(row0 + (c0 >> 2)) * K + (c0 & 3) * 8;
    a1 = A + (size_t)(row0 + (c1 >> 2)) * K + (c1 & 3) * 8;
  }
  const f16* b0 = BTz + (size_t)(col0 + (c0 >> 2)) * K + (c0 & 3) * 8;
  const f16* b1 = BTz + (size_t)(col0 + (c1 >> 2)) * K + (c1 & 3) * 8;
  const int da0 = wid * 512, da1 = 2048 + wid * 512;

  const floatx4 zero4 = {0.f, 0.f, 0.f, 0.f};
  floatx4 acc[4][4];
#pragma unroll
  for (int m = 0; m < 4; ++m)
#pragma unroll
    for (int n = 0; n < 4; ++n) acc[m][n] = zero4;

  int kst = 0;
  auto issue = [&](int buf) {
    gll16(a0, &SB[buf][da0]);
    gll16(a1, &SB[buf][da1]);
    gll16(b0, &SB[buf][4096 + da0]);
    gll16(b1, &SB[buf][4096 + da1]);
    if constexpr (A_HM) {
      // k advances 32/step; head block (64 wide) spans 2 steps; stride 131072/head
      const int adv = (kst & 1) ? (131072 - 32) : 32;
      a0 += adv; a1 += adv;
      ++kst;
    } else {
      a0 += 32; a1 += 32;
    }
    b0 += 32; b1 += 32;
  };

  const int nstep = K >> 5;
  issue(0);

  auto step = [&](int buf, int t) {
    asm volatile("s_waitcnt vmcnt(0)" ::: "memory");
    __builtin_amdgcn_s_barrier();
    asm volatile("" ::: "memory");
    if (t + 1 < nstep) issue(buf ^ 1);
    const f16* As = &SB[buf][0];
    const f16* Bs = &SB[buf][4096];
    half8 af[4], bf[4];
#pragma unroll
    for (int m = 0; m < 4; ++m)
      af[m] = *(const half8*)&As[(wr + m * 16 + li) * 32 + lg * 8];
#pragma unroll
    for (int n = 0; n < 4; ++n)
      bf[n] = *(const half8*)&Bs[(wc + n * 16 + li) * 32 + lg * 8];
#pragma unroll
    for (int m = 0; m < 4; ++m)
#pragma unroll
      for (int n = 0; n < 4; ++n)
        acc[m][n] = __builtin_amdgcn_mfma_f32_16x16x32_f16(af[m], bf[n], acc[m][n], 0, 0, 0);
  };

  for (int t2 = 0; t2 < nstep; t2 += 2) {
    step(0, t2);
    step(1, t2 + 1);
  }

#pragma unroll
  for (int m = 0; m < 4; ++m)
#pragma unroll
    for (int n = 0; n < 4; ++n)
#pragma unroll
      for (int r = 0; r < 4; ++r) {
        const int row = row0 + wr + m * 16 + lg * 4 + r;
        const int col = col0 + wc + n * 16 + li;
        if constexpr (OUT_F32) {
          float* C = (float*)Cptr + (size_t)blockIdx.z * c_zstride;
          C[(size_t)row * N + col] = acc[m][n][r] + bias[col];
        } else {
          f16* C = (f16*)Cptr + (size_t)blockIdx.z * c_zstride;
          C[(size_t)row * N + col] = (f16)acc[m][n][r];
        }
      }
}

// ---- flash attention v6: grid-level KV-split-4, 4-wave blocks, 32KB LDS ----
__global__ __launch_bounds__(256) void k_attn6(
    const f16* __restrict__ qh, const f16* __restrict__ kh,
    const f16* __restrict__ vt, f16* __restrict__ p01, f16* __restrict__ p23,
    float* __restrict__ mArr, float* __restrict__ lArr)
{
  __shared__ f16 KV[2][8192];   // exactly 32768 B: [buf][K 0..4095 | V^T 4096..8191]

  const int tid = threadIdx.x;
  const int lane = tid & 63;
  const int wid = tid >> 6;   // q-subtile 0..3
  const int col = lane & 31;
  const int hi = lane >> 5;

  // 2048 blocks: xcd(3b) | bh-sub(2b) | s4(2b) | qi(4b)
  const int id = blockIdx.x;
  const int xcd = id & 7;
  const int j = id >> 3;          // 0..255
  const int bh = xcd * 4 + (j >> 6);
  const int rem = j & 63;
  const int s4 = rem >> 4;        // kv quarter
  const int qi = rem & 15;
  const int b = bh >> 4, h = bh & 15;

  const int q0 = qi * 128 + wid * 32;
  const int kv0 = s4 * 512;
  const size_t xbase = (size_t)b * SEQ * DIM + (size_t)h * DH;
  const size_t vtbase = (size_t)bh * DH * SEQ;

  const float SC = 0.125f * 1.44269504089f;  // scale * log2(e)
  const float RTRAW = 8.0f / SC;

  const int c0 = tid, c1 = tid + 256;
  const int r0 = c0 >> 3, sw0 = ((c0 & 7) ^ (r0 & 7)) * 8;
  const int r1 = c1 >> 3, sw1 = ((c1 & 7) ^ (r1 & 7)) * 8;
  const f16* ks0 = kh + xbase + (size_t)(kv0 + r0) * DIM + sw0;
  const f16* ks1 = kh + xbase + (size_t)(kv0 + r1) * DIM + sw1;
  const f16* vs0 = vt + vtbase + (size_t)r0 * SEQ + kv0 + sw0;
  const f16* vs1 = vt + vtbase + (size_t)r1 * SEQ + kv0 + sw1;
  const int db0 = wid * 512, db1 = 2048 + wid * 512;

  auto issue = [&](int buf) {
    f16* B = &KV[buf][0];
    gll16(ks0, B + db0);
    gll16(ks1, B + db1);
    gll16(vs0, B + 4096 + db0);
    gll16(vs1, B + 4096 + db1);
    ks0 += 64 * DIM; ks1 += 64 * DIM; vs0 += 64; vs1 += 64;
  };

  half8 qb[4];
  {
    const f16* qrow = qh + xbase + (size_t)(q0 + col) * DIM;
#pragma unroll
    for (int s = 0; s < 4; ++s) qb[s] = *(const half8*)(qrow + s * 16 + hi * 8);
  }

  f32x16 o0 = {0, 0, 0, 0, 0, 0, 0, 0, 0, 0, 0, 0, 0, 0, 0, 0};
  f32x16 o1 = {0, 0, 0, 0, 0, 0, 0, 0, 0, 0, 0, 0, 0, 0, 0, 0};
  float m = -1e30f, lsum = 0.f;

  issue(0);

  auto tile = [&](int buf, int t) {
    asm volatile("s_waitcnt vmcnt(0)" ::: "memory");
    __builtin_amdgcn_s_barrier();
    asm volatile("" ::: "memory");
    if (t < 7) issue(buf ^ 1);
    const f16* Ks = &KV[buf][0];
    const f16* Vs = &KV[buf][4096];

#pragma unroll
    for (int kvs = 0; kvs < 2; ++kvs) {
      const int krow = kvs * 32 + col;
      f32x16 sacc = {0, 0, 0, 0, 0, 0, 0, 0, 0, 0, 0, 0, 0, 0, 0, 0};
      __builtin_amdgcn_s_setprio(1);
#pragma unroll
      for (int s = 0; s < 4; ++s) {
        const int cc = (2 * s + hi) ^ (krow & 7);
        half8 ka = *(const half8*)&Ks[krow * 64 + cc * 8];
        sacc = __builtin_amdgcn_mfma_f32_32x32x16_f16(ka, qb[s], sacc, 0, 0, 0);
      }
      __builtin_amdgcn_s_setprio(0);

      float x0 = fmaxf(fmaxf(sacc[0], sacc[1]), fmaxf(sacc[2], sacc[3]));
      float x1 = fmaxf(fmaxf(sacc[4], sacc[5]), fmaxf(sacc[6], sacc[7]));
      float x2 = fmaxf(fmaxf(sacc[8], sacc[9]), fmaxf(sacc[10], sacc[11]));
      float x3 = fmaxf(fmaxf(sacc[12], sacc[13]), fmaxf(sacc[14], sacc[15]));
      float smax = fmaxf(fmaxf(x0, x1), fmaxf(x2, x3));
      smax = fmaxf(smax, __shfl_xor(smax, 32));

      if (!__all(smax <= m + RTRAW)) {
        const float mn = fmaxf(m, smax);
        const float alpha = fexp2((m - mn) * SC);
        m = mn;
        lsum *= alpha;
#pragma unroll
        for (int r = 0; r < 16; ++r) {
          const float a2 = __shfl(alpha, (r & 3) + 8 * (r >> 2) + 4 * hi);
          o0[r] *= a2;
          o1[r] *= a2;
        }
      }

      const float mc = m * SC;
      float pw[16];
#pragma unroll
      for (int r = 0; r < 16; ++r) pw[r] = fexp2(fmaf(sacc[r], SC, -mc));
      float t0 = (pw[0] + pw[1]) + (pw[2] + pw[3]);
      float t1 = (pw[4] + pw[5]) + (pw[6] + pw[7]);
      float t2 = (pw[8] + pw[9]) + (pw[10] + pw[11]);
      float t3 = (pw[12] + pw[13]) + (pw[14] + pw[15]);
      float rs = (t0 + t1) + (t2 + t3);
      rs += __shfl_xor(rs, 32);
      lsum += rs;

      __builtin_amdgcn_s_setprio(1);
#pragma unroll
      for (int s2i = 0; s2i < 2; ++s2i) {
        const int rb = s2i * 8;
        unsigned X0 = pkrtz(pw[rb + 0], pw[rb + 1]);
        unsigned X1 = pkrtz(pw[rb + 2], pw[rb + 3]);
        unsigned Y0 = pkrtz(pw[rb + 4], pw[rb + 5]);
        unsigned Y1 = pkrtz(pw[rb + 6], pw[rb + 7]);
        pl32swap(X0, Y0);
        pl32swap(X1, Y1);
        const half8 paf = __builtin_bit_cast(half8, (uint4v){X0, X1, Y0, Y1});
        const int kc = kvs * 4 + s2i * 2 + hi;
#pragma unroll
        for (int dt = 0; dt < 2; ++dt) {
          const int vrow = dt * 32 + col;
          const int cc = kc ^ (vrow & 7);
          half8 vb = *(const half8*)&Vs[vrow * 64 + cc * 8];
          if (dt == 0)
            o0 = __builtin_amdgcn_mfma_f32_32x32x16_f16(paf, vb, o0, 0, 0, 0);
          else
            o1 = __builtin_amdgcn_mfma_f32_32x32x16_f16(paf, vb, o1, 0, 0, 0);
        }
      }
      __builtin_amdgcn_s_setprio(0);
    }
  };

  for (int t2 = 0; t2 < 8; t2 += 2) {
    tile(0, t2);
    tile(1, t2 + 1);
  }

  const int gq = bh * 2048 + q0;
  const float inv = 1.0f / lsum;
  if (hi == 0) {
    mArr[s4 * QTOT + gq + col] = m * SC;   // exp2-domain max
    lArr[s4 * QTOT + gq + col] = lsum;
  }
  f16* pb = (s4 & 2) ? p23 : p01;
  pb += (size_t)(s4 & 1) * QTOT * DH;
  f16* prow = pb + (size_t)gq * DH;
#pragma unroll
  for (int r = 0; r < 16; ++r) {
    const int qr = (r & 3) + 8 * (r >> 2) + 4 * hi;
    const float iv = __shfl(inv, qr);
    prow[qr * DH + col] = (f16)(o0[r] * iv);
    prow[qr * DH + 32 + col] = (f16)(o1[r] * iv);
  }
}

// ---- merge 4 normalized partials -> fp16 attn output, head-major [bh][n][64]
//      (in-place over the p3 region; per-thread read-before-write) ----
__global__ __launch_bounds__(256) void k_merge(
    const f16* __restrict__ p01, const f16* __restrict__ p23,
    const float* __restrict__ mArr, const float* __restrict__ lArr,
    f16* __restrict__ out)
{
  const int t = blockIdx.x * 256 + threadIdx.x;  // 524288 threads
  const int q = t >> 3;
  const int d8 = (t & 7) * 8;

  float mv[4], lv[4];
#pragma unroll
  for (int s = 0; s < 4; ++s) {
    mv[s] = mArr[s * QTOT + q];
    lv[s] = lArr[s * QTOT + q];
  }
  const float M = fmaxf(fmaxf(mv[0], mv[1]), fmaxf(mv[2], mv[3]));
  float w[4], den = 0.f;
#pragma unroll
  for (int s = 0; s < 4; ++s) {
    w[s] = lv[s] * fexp2(mv[s] - M);
    den += w[s];
  }
  const float rd = 1.0f / den;

  float a[8] = {0, 0, 0, 0, 0, 0, 0, 0};
#pragma unroll
  for (int s = 0; s < 4; ++s) {
    const f16* pb = (s & 2) ? p23 : p01;
    pb += (size_t)(s & 1) * QTOT * DH;
    half8 v = *(const half8*)(pb + (size_t)q * DH + d8);
#pragma unroll
    for (int jj = 0; jj < 8; ++jj) a[jj] = fmaf(w[s], (float)v[jj], a[jj]);
  }
  half8 o;
#pragma unroll
  for (int jj = 0; jj < 8; ++jj) o[jj] = (f16)(a[jj] * rd);
  *(half8*)(out + (size_t)q * DH + d8) = o;
}

extern "C" void kernel_launch(void* const* d_in, const int* in_sizes, int n_in,
                              void* d_out, int out_size, void* d_ws, size_t ws_size,
                              hipStream_t stream)
{
  const float* x  = (const float*)d_in[0];
  const float* Wq = (const float*)d_in[1];
  const float* Wk = (const float*)d_in[2];
  const float* Wv = (const float*)d_in[3];
  const float* Wo = (const float*)d_in[4];
  const float* bo = (const float*)d_in[5];

  char* ws = (char*)d_ws;
  f16* wt   = (f16*)ws;                               // 8 MB (wq/wk/wv dead after QKV GEMM)
  f16* qkvh = (f16*)(ws + (size_t)8 * 1024 * 1024);   // q 8-16, k 16-24, v 24-32 MB
  f16* ohp  = (f16*)(ws + (size_t)32 * 1024 * 1024);  // 8 MB (aliases xh / p3)
  f16* vtb  = (f16*)(ws + (size_t)40 * 1024 * 1024);  // 8 MB
  f16* xh   = ohp;  // x-fp16 consumed by QKV GEMM before attn writes p3 here

  // attn partial scratch (all dead-at-that-point regions):
  f16* p01 = (f16*)d_out;                             // 16 MB, overwritten by final GEMM
  f16* p23 = qkvh + (size_t)2 * MTOT * DIM;           // 24-40 MB: dead V + dead xh
  float* mArr = (float*)ws;                           // 1 MB over dead wq^T
  float* lArr = (float*)(ws + (size_t)1024 * 1024);   // 1 MB over dead wq^T

  k_transpose<<<dim3(32, 32, 4), dim3(32, 8), 0, stream>>>(Wq, Wk, Wv, Wo, wt);

  k_xcast<<<2048, 256, 0, stream>>>(x, xh);

  k_gemm2<false, false><<<dim3(32, 8, 3), 256, 0, stream>>>(
      xh, wt, qkvh, nullptr, MTOT, DIM, DIM,
      (size_t)DIM * DIM, (size_t)MTOT * DIM);

  k_vtrans<<<dim3(32, 32), 256, 0, stream>>>(
      qkvh + (size_t)2 * MTOT * DIM, vtb);

  k_attn6<<<2048, 256, 0, stream>>>(
      qkvh, qkvh + (size_t)MTOT * DIM, vtb, p01, p23, mArr, lArr);

  k_merge<<<2048, 256, 0, stream>>>(p01, p23, mArr, lArr, ohp);

  // out-projection reads ohp in head-major layout (A_HM=true)
  k_gemm2<true, true><<<dim3(32, 8, 1), 256, 0, stream>>>(
      ohp, wt + (size_t)3 * DIM * DIM, d_out, bo, MTOT, DIM, DIM, 0, 0);
}

// Round 9
// 122.577 us; speedup vs baseline: 1.1047x; 1.1047x over previous
//
#include <hip/hip_runtime.h>
#include <hip/hip_fp16.h>

typedef _Float16 f16;
typedef __attribute__((ext_vector_type(8))) _Float16 half8;
typedef __attribute__((ext_vector_type(2))) __fp16 fp16x2_native;
typedef __attribute__((ext_vector_type(4))) float floatx4;
typedef __attribute__((ext_vector_type(16))) float f32x16;
typedef __attribute__((ext_vector_type(4))) unsigned uint4v;
typedef __attribute__((ext_vector_type(2))) unsigned uint2v;

static constexpr int DIM = 1024;
static constexpr int SEQ = 2048;
static constexpr int DH = 64;
static constexpr int MTOT = 4096;  // BATCH * SEQ

__device__ __forceinline__ float fexp2(float x) {
#if __has_builtin(__builtin_amdgcn_exp2f)
  return __builtin_amdgcn_exp2f(x);
#else
  return exp2f(x);
#endif
}

__device__ __forceinline__ unsigned pkrtz(float a, float b) {
  fp16x2_native h = __builtin_amdgcn_cvt_pkrtz(a, b);
  return __builtin_bit_cast(unsigned, h);
}

__device__ __forceinline__ void pl32swap(unsigned& a, unsigned& b) {
#if __has_builtin(__builtin_amdgcn_permlane32_swap)
  uint2v r = __builtin_amdgcn_permlane32_swap(a, b, false, false);
  a = r.x;
  b = r.y;
#else
  asm volatile("v_permlane32_swap_b32 %0, %1" : "+v"(a), "+v"(b));
#endif
}

// async global->LDS 16B
__device__ __forceinline__ void gll16(const f16* g, f16* l) {
  auto gp = (__attribute__((address_space(1))) unsigned*)(uintptr_t)(const void*)g;
  auto lp = (__attribute__((address_space(3))) unsigned*)(uintptr_t)(void*)l;
  __builtin_amdgcn_global_load_lds(gp, lp, 16, 0, 0);
}

// ---- weight transpose + fp16 convert: wt[z][n][k] = W_z[k][n] ----
__global__ __launch_bounds__(256) void k_transpose(
    const float* __restrict__ Wq, const float* __restrict__ Wk,
    const float* __restrict__ Wv, const float* __restrict__ Wo,
    f16* __restrict__ wt)
{
  __shared__ float tile[32][33];
  const int z = blockIdx.z;
  const float* W = (z == 0) ? Wq : (z == 1) ? Wk : (z == 2) ? Wv : Wo;
  f16* out = wt + (size_t)z * DIM * DIM;
  const int tx = threadIdx.x, ty = threadIdx.y;
  const int x0 = blockIdx.x * 32, y0 = blockIdx.y * 32;
#pragma unroll
  for (int i = 0; i < 4; ++i)
    tile[ty + i * 8][tx] = W[(size_t)(y0 + ty + i * 8) * DIM + (x0 + tx)];
  __syncthreads();
#pragma unroll
  for (int i = 0; i < 4; ++i)
    out[(size_t)(x0 + ty + i * 8) * DIM + (y0 + tx)] = (f16)tile[tx][ty + i * 8];
}

// ---- x fp32 -> fp16 ----
__global__ __launch_bounds__(256) void k_xcast(
    const float* __restrict__ in, f16* __restrict__ out)
{
  const int i = blockIdx.x * 256 + threadIdx.x;
  const float4* p = (const float4*)in;
  float4 a = p[2 * i], b = p[2 * i + 1];
  half8 h = {(f16)a.x, (f16)a.y, (f16)a.z, (f16)a.w,
             (f16)b.x, (f16)b.y, (f16)b.z, (f16)b.w};
  *(half8*)(out + (size_t)i * 8) = h;
}

// ---- V^T pre-transpose: vt[bh][d][n] = V[b][n][h*64+d] ----
__global__ __launch_bounds__(256) void k_vtrans(
    const f16* __restrict__ vh, f16* __restrict__ vt)
{
  __shared__ f16 T[64][72];
  const int tid = threadIdx.x;
  const int nt = blockIdx.x, bh = blockIdx.y;
  const int b = bh >> 4, h = bh & 15;
  const int n0 = nt * 64;
  const f16* src = vh + (size_t)b * SEQ * DIM + (size_t)h * DH;
#pragma unroll
  for (int i = 0; i < 2; ++i) {
    const int n = (tid >> 3) + i * 32;
    const int cc = tid & 7;
    half8 v = *(const half8*)(src + (size_t)(n0 + n) * DIM + cc * 8);
#pragma unroll
    for (int j = 0; j < 8; ++j) T[cc * 8 + j][n] = v[j];
  }
  __syncthreads();
  f16* dst = vt + (size_t)bh * DH * SEQ;
#pragma unroll
  for (int i = 0; i < 2; ++i) {
    const int d = (tid >> 3) + i * 32;
    const int cc = tid & 7;
    half8 w = *(const half8*)&T[d][cc * 8];
    *(half8*)(dst + (size_t)d * SEQ + n0 + cc * 8) = w;
  }
}

// ---- fp16 GEMM, 128x128 tile, BK=32, gll double-buffer, 1 barrier/step ----
template <bool OUT_F32>
__global__ __launch_bounds__(256) void k_gemm2(
    const f16* __restrict__ A, const f16* __restrict__ BT,
    void* __restrict__ Cptr, const float* __restrict__ bias,
    int M, int N, int K, size_t bt_zstride, size_t c_zstride)
{
  __shared__ f16 SB[2][8192];

  const int tid = threadIdx.x;
  const int lane = tid & 63;
  const int wid = tid >> 6;
  const int wr = (wid >> 1) * 64, wc = (wid & 1) * 64;
  const int li = lane & 15, lg = lane >> 4;

  const f16* BTz = BT + (size_t)blockIdx.z * bt_zstride;
  const int row0 = blockIdx.x * 128, col0 = blockIdx.y * 128;

  const int c0 = tid;
  const int c1 = 256 + tid;
  const f16* a0 = A + (size_t)(row0 + (c0 >> 2)) * K + (c0 & 3) * 8;
  const f16* a1 = A + (size_t)(row0 + (c1 >> 2)) * K + (c1 & 3) * 8;
  const f16* b0 = BTz + (size_t)(col0 + (c0 >> 2)) * K + (c0 & 3) * 8;
  const f16* b1 = BTz + (size_t)(col0 + (c1 >> 2)) * K + (c1 & 3) * 8;
  const int da0 = wid * 512, da1 = 2048 + wid * 512;

  const floatx4 zero4 = {0.f, 0.f, 0.f, 0.f};
  floatx4 acc[4][4];
#pragma unroll
  for (int m = 0; m < 4; ++m)
#pragma unroll
    for (int n = 0; n < 4; ++n) acc[m][n] = zero4;

  auto issue = [&](int buf) {
    gll16(a0, &SB[buf][da0]);
    gll16(a1, &SB[buf][da1]);
    gll16(b0, &SB[buf][4096 + da0]);
    gll16(b1, &SB[buf][4096 + da1]);
    a0 += 32; a1 += 32; b0 += 32; b1 += 32;
  };

  const int nstep = K >> 5;
  issue(0);

  auto step = [&](int buf, int t) {
    asm volatile("s_waitcnt vmcnt(0)" ::: "memory");
    __builtin_amdgcn_s_barrier();
    asm volatile("" ::: "memory");
    if (t + 1 < nstep) issue(buf ^ 1);
    const f16* As = &SB[buf][0];
    const f16* Bs = &SB[buf][4096];
    half8 af[4], bf[4];
#pragma unroll
    for (int m = 0; m < 4; ++m)
      af[m] = *(const half8*)&As[(wr + m * 16 + li) * 32 + lg * 8];
#pragma unroll
    for (int n = 0; n < 4; ++n)
      bf[n] = *(const half8*)&Bs[(wc + n * 16 + li) * 32 + lg * 8];
#pragma unroll
    for (int m = 0; m < 4; ++m)
#pragma unroll
      for (int n = 0; n < 4; ++n)
        acc[m][n] = __builtin_amdgcn_mfma_f32_16x16x32_f16(af[m], bf[n], acc[m][n], 0, 0, 0);
  };

  for (int t2 = 0; t2 < nstep; t2 += 2) {
    step(0, t2);
    step(1, t2 + 1);
  }

#pragma unroll
  for (int m = 0; m < 4; ++m)
#pragma unroll
    for (int n = 0; n < 4; ++n)
#pragma unroll
      for (int r = 0; r < 4; ++r) {
        const int row = row0 + wr + m * 16 + lg * 4 + r;
        const int col = col0 + wc + n * 16 + li;
        if constexpr (OUT_F32) {
          float* C = (float*)Cptr + (size_t)blockIdx.z * c_zstride;
          C[(size_t)row * N + col] = acc[m][n][r] + bias[col];
        } else {
          f16* C = (f16*)Cptr + (size_t)blockIdx.z * c_zstride;
          C[(size_t)row * N + col] = (f16)acc[m][n][r];
        }
      }
}

// ---- flash attention v7: 8 waves, intra-block KV split, gll double-buffer,
//      wave-global running max (no in-loop cross-lane), speculative exp2,
//      unrolled 2-kvs pipeline ----
__global__ __launch_bounds__(512) void k_attn7(
    const f16* __restrict__ qh, const f16* __restrict__ kh,
    const f16* __restrict__ vt, f16* __restrict__ oh)
{
  __shared__ f16 KV[2][16384];   // [buf][K0|V0|K1|V1] 4096 f16 each, 16B-col swizzled
  __shared__ float bc[8][32];
  __shared__ float Lm[4][32], Ll[4][32], W0[4][32], W1[4][32];

  const int tid = threadIdx.x;
  const int lane = tid & 63;
  const int wid = tid >> 6;   // 0..7
  const int g = wid >> 2;     // kv-half group
  const int sub = wid & 3;    // q-subtile
  const int col = lane & 31;
  const int hi = lane >> 5;

  // XCD-bijective swizzle: 512 blocks, XCD owns 4 consecutive bh
  const int id = blockIdx.x;
  const int xcd = id & 7;
  const int j = id >> 3;
  const int bh = xcd * 4 + (j >> 4);
  const int qi = j & 15;
  const int b = bh >> 4, h = bh & 15;

  const int q0 = qi * 128 + sub * 32;
  const size_t xbase = (size_t)b * SEQ * DIM + (size_t)h * DH;
  const size_t vtbase = (size_t)bh * DH * SEQ;

  const float SC = 0.125f * 1.44269504089f;  // scale * log2(e)
  const float RTRAW = 8.0f / SC;

  // staging: each thread issues 4 gll16/step (K0,V0,K1,V1)
  const int lc = tid & 511;
  const int srow = lc >> 3;
  const int sw = ((lc & 7) ^ (srow & 7)) * 8;
  const f16* ks0 = kh + xbase + (size_t)srow * DIM + sw;
  const f16* ks1 = kh + xbase + (size_t)(1024 + srow) * DIM + sw;
  const f16* vs0 = vt + vtbase + (size_t)srow * SEQ + sw;
  const f16* vs1 = vt + vtbase + (size_t)srow * SEQ + 1024 + sw;

  auto issue = [&](int buf) {
    f16* B = &KV[buf][wid * 512];
    gll16(ks0, B);
    gll16(vs0, B + 4096);
    gll16(ks1, B + 8192);
    gll16(vs1, B + 12288);
    ks0 += 64 * DIM; ks1 += 64 * DIM; vs0 += 64; vs1 += 64;
  };

  // Q fragments (B-operand)
  half8 qb[4];
  {
    const f16* qrow = qh + xbase + (size_t)(q0 + col) * DIM;
#pragma unroll
    for (int s = 0; s < 4; ++s) qb[s] = *(const half8*)(qrow + s * 16 + hi * 8);
  }

  f32x16 o0 = {0, 0, 0, 0, 0, 0, 0, 0, 0, 0, 0, 0, 0, 0, 0, 0};
  f32x16 o1 = {0, 0, 0, 0, 0, 0, 0, 0, 0, 0, 0, 0, 0, 0, 0, 0};
  float m = -1e30f, mc = 0.f;   // wave-global running max (raw / exp2-domain)
  float lsum = 0.f;             // per-lane partial; combined once at end

  issue(0);

  // softmax + PV for one 32-kv slice held in sacc
  auto process = [&](const f32x16& sacc, int kvs, const f16* Vs) {
    // speculative exp2 with current m (recomputed only on rare rescale)
    float pw[16];
#pragma unroll
    for (int r = 0; r < 16; ++r) pw[r] = fexp2(fmaf(sacc[r], SC, -mc));

    float x0 = fmaxf(fmaxf(sacc[0], sacc[1]), fmaxf(sacc[2], sacc[3]));
    float x1 = fmaxf(fmaxf(sacc[4], sacc[5]), fmaxf(sacc[6], sacc[7]));
    float x2 = fmaxf(fmaxf(sacc[8], sacc[9]), fmaxf(sacc[10], sacc[11]));
    float x3 = fmaxf(fmaxf(sacc[12], sacc[13]), fmaxf(sacc[14], sacc[15]));
    const float smax = fmaxf(fmaxf(x0, x1), fmaxf(x2, x3));

    if (!__all(smax <= m + RTRAW)) {  // rare (first tile + outliers)
      float wm = smax;
#pragma unroll
      for (int off = 1; off < 64; off <<= 1) wm = fmaxf(wm, __shfl_xor(wm, off));
      const float mn = fmaxf(m, wm);
      const float alpha = fexp2((m - mn) * SC);  // wave-uniform
      m = mn;
      mc = m * SC;
      lsum *= alpha;
#pragma unroll
      for (int r = 0; r < 16; ++r) { o0[r] *= alpha; o1[r] *= alpha; }
#pragma unroll
      for (int r = 0; r < 16; ++r) pw[r] = fexp2(fmaf(sacc[r], SC, -mc));
    }

    float t0 = (pw[0] + pw[1]) + (pw[2] + pw[3]);
    float t1 = (pw[4] + pw[5]) + (pw[6] + pw[7]);
    float t2 = (pw[8] + pw[9]) + (pw[10] + pw[11]);
    float t3 = (pw[12] + pw[13]) + (pw[14] + pw[15]);
    lsum += (t0 + t1) + (t2 + t3);

    __builtin_amdgcn_s_setprio(1);
#pragma unroll
    for (int s2i = 0; s2i < 2; ++s2i) {
      const int rb = s2i * 8;
      unsigned X0 = pkrtz(pw[rb + 0], pw[rb + 1]);
      unsigned X1 = pkrtz(pw[rb + 2], pw[rb + 3]);
      unsigned Y0 = pkrtz(pw[rb + 4], pw[rb + 5]);
      unsigned Y1 = pkrtz(pw[rb + 6], pw[rb + 7]);
      pl32swap(X0, Y0);
      pl32swap(X1, Y1);
      const half8 paf = __builtin_bit_cast(half8, (uint4v){X0, X1, Y0, Y1});
      const int kc = kvs * 4 + s2i * 2 + hi;
#pragma unroll
      for (int dt = 0; dt < 2; ++dt) {
        const int vrow = dt * 32 + col;
        const int cc = kc ^ (vrow & 7);
        half8 vb = *(const half8*)&Vs[vrow * 64 + cc * 8];
        if (dt == 0)
          o0 = __builtin_amdgcn_mfma_f32_32x32x16_f16(paf, vb, o0, 0, 0, 0);
        else
          o1 = __builtin_amdgcn_mfma_f32_32x32x16_f16(paf, vb, o1, 0, 0, 0);
      }
    }
    __builtin_amdgcn_s_setprio(0);
  };

  auto tile = [&](int buf, int t) {
    asm volatile("s_waitcnt vmcnt(0)" ::: "memory");
    __builtin_amdgcn_s_barrier();
    asm volatile("" ::: "memory");
    if (t < 15) issue(buf ^ 1);
    const f16* Ks = &KV[buf][g * 8192];
    const f16* Vs = Ks + 4096;

    // both QK^T slices upfront (separate regs -> PV/softmax can overlap)
    f32x16 sa = {0, 0, 0, 0, 0, 0, 0, 0, 0, 0, 0, 0, 0, 0, 0, 0};
    f32x16 sb = {0, 0, 0, 0, 0, 0, 0, 0, 0, 0, 0, 0, 0, 0, 0, 0};
    __builtin_amdgcn_s_setprio(1);
#pragma unroll
    for (int s = 0; s < 4; ++s) {
      const int cc = (2 * s + hi) ^ (col & 7);
      half8 ka = *(const half8*)&Ks[col * 64 + cc * 8];
      sa = __builtin_amdgcn_mfma_f32_32x32x16_f16(ka, qb[s], sa, 0, 0, 0);
    }
#pragma unroll
    for (int s = 0; s < 4; ++s) {
      const int krow = 32 + col;
      const int cc = (2 * s + hi) ^ (krow & 7);
      half8 ka = *(const half8*)&Ks[krow * 64 + cc * 8];
      sb = __builtin_amdgcn_mfma_f32_32x32x16_f16(ka, qb[s], sb, 0, 0, 0);
    }
    __builtin_amdgcn_s_setprio(0);

    process(sa, 0, Vs);
    process(sb, 1, Vs);
  };

  for (int t2 = 0; t2 < 16; t2 += 2) {
    tile(0, t2);
    tile(1, t2 + 1);
  }

  lsum += __shfl_xor(lsum, 32);  // full row-sum for q = col

  // ---- merge the two kv-half partials via LDS (differing wave-global m) ----
  if (g == 1) {
    const float inv = 1.0f / lsum;
    if (hi == 0) { Lm[sub][col] = m; Ll[sub][col] = lsum; bc[wid][col] = inv; }
    f16* po = &KV[0][0] + sub * 2048;  // 32 rows x 64 cols fp16, normalized
#pragma unroll
    for (int r = 0; r < 16; ++r) {
      const int qr = (r & 3) + 8 * (r >> 2) + 4 * hi;
      const float iv = bc[wid][qr];
      po[qr * 64 + col] = (f16)(o0[r] * iv);
      po[qr * 64 + 32 + col] = (f16)(o1[r] * iv);
    }
  }
  __syncthreads();
  if (g == 0) {
    const float m1 = Lm[sub][col], l1 = Ll[sub][col];
    const float M = fmaxf(m, m1);
    const float e0 = fexp2((m - M) * SC);
    const float a0 = lsum * e0;
    const float a1 = l1 * fexp2((m1 - M) * SC);
    const float rden = 1.0f / (a0 + a1);
    const float c0 = e0 * rden;   // applies to RAW o0/o1
    const float w1 = a1 * rden;   // applies to NORMALIZED partial
    if (hi == 0) { W0[sub][col] = c0; W1[sub][col] = w1; }
    const f16* po = &KV[0][0] + sub * 2048;
#pragma unroll
    for (int r = 0; r < 16; ++r) {
      const int qr = (r & 3) + 8 * (r >> 2) + 4 * hi;
      const float c0r = W0[sub][qr], w1r = W1[sub][qr];
      f16* orow = oh + xbase + (size_t)(q0 + qr) * DIM;
      orow[col] = (f16)(c0r * o0[r] + w1r * (float)po[qr * 64 + col]);
      orow[32 + col] = (f16)(c0r * o1[r] + w1r * (float)po[qr * 64 + 32 + col]);
    }
  }
}

extern "C" void kernel_launch(void* const* d_in, const int* in_sizes, int n_in,
                              void* d_out, int out_size, void* d_ws, size_t ws_size,
                              hipStream_t stream)
{
  const float* x  = (const float*)d_in[0];
  const float* Wq = (const float*)d_in[1];
  const float* Wk = (const float*)d_in[2];
  const float* Wv = (const float*)d_in[3];
  const float* Wo = (const float*)d_in[4];
  const float* bo = (const float*)d_in[5];

  char* ws = (char*)d_ws;
  f16* wt   = (f16*)ws;                               // 8 MB
  f16* qkvh = (f16*)(ws + (size_t)8 * 1024 * 1024);   // 24 MB
  f16* ohp  = (f16*)(ws + (size_t)32 * 1024 * 1024);  // 8 MB (aliases xh)
  f16* vtb  = (f16*)(ws + (size_t)40 * 1024 * 1024);  // 8 MB
  f16* xh   = ohp;  // x-fp16 consumed by QKV GEMM before attn writes ohp

  k_transpose<<<dim3(32, 32, 4), dim3(32, 8), 0, stream>>>(Wq, Wk, Wv, Wo, wt);

  k_xcast<<<2048, 256, 0, stream>>>(x, xh);

  k_gemm2<false><<<dim3(32, 8, 3), 256, 0, stream>>>(
      xh, wt, qkvh, nullptr, MTOT, DIM, DIM,
      (size_t)DIM * DIM, (size_t)MTOT * DIM);

  k_vtrans<<<dim3(32, 32), 256, 0, stream>>>(
      qkvh + (size_t)2 * MTOT * DIM, vtb);

  k_attn7<<<512, 512, 0, stream>>>(
      qkvh, qkvh + (size_t)MTOT * DIM, vtb, ohp);

  k_gemm2<true><<<dim3(32, 8, 1), 256, 0, stream>>>(
      ohp, wt + (size_t)3 * DIM * DIM, d_out, bo, MTOT, DIM, DIM, 0, 0);
}

// Round 11
// 116.526 us; speedup vs baseline: 1.1621x; 1.0519x over previous
//
#include <hip/hip_runtime.h>
#include <hip/hip_fp16.h>

typedef _Float16 f16;
typedef __attribute__((ext_vector_type(8))) _Float16 half8;
typedef __attribute__((ext_vector_type(2))) __fp16 fp16x2_native;
typedef __attribute__((ext_vector_type(4))) float floatx4;
typedef __attribute__((ext_vector_type(16))) float f32x16;
typedef __attribute__((ext_vector_type(4))) unsigned uint4v;
typedef __attribute__((ext_vector_type(2))) unsigned uint2v;

static constexpr int DIM = 1024;
static constexpr int SEQ = 2048;
static constexpr int DH = 64;
static constexpr int MTOT = 4096;  // BATCH * SEQ

__device__ __forceinline__ float fexp2(float x) {
#if __has_builtin(__builtin_amdgcn_exp2f)
  return __builtin_amdgcn_exp2f(x);
#else
  return exp2f(x);
#endif
}

__device__ __forceinline__ unsigned pkrtz(float a, float b) {
  fp16x2_native h = __builtin_amdgcn_cvt_pkrtz(a, b);
  return __builtin_bit_cast(unsigned, h);
}

__device__ __forceinline__ void pl32swap(unsigned& a, unsigned& b) {
#if __has_builtin(__builtin_amdgcn_permlane32_swap)
  uint2v r = __builtin_amdgcn_permlane32_swap(a, b, false, false);
  a = r.x;
  b = r.y;
#else
  asm volatile("v_permlane32_swap_b32 %0, %1" : "+v"(a), "+v"(b));
#endif
}

// async global->LDS 16B
__device__ __forceinline__ void gll16(const f16* g, f16* l) {
  auto gp = (__attribute__((address_space(1))) unsigned*)(uintptr_t)(const void*)g;
  auto lp = (__attribute__((address_space(3))) unsigned*)(uintptr_t)(void*)l;
  __builtin_amdgcn_global_load_lds(gp, lp, 16, 0, 0);
}

// ---- prep: z<4 = weight transpose+fp16 (wt[z][n][k]=W_z[k][n]); z==4 = x fp32->fp16 ----
__global__ __launch_bounds__(256) void k_prep(
    const float* __restrict__ Wq, const float* __restrict__ Wk,
    const float* __restrict__ Wv, const float* __restrict__ Wo,
    const float* __restrict__ x, f16* __restrict__ wt, f16* __restrict__ xh)
{
  const int z = blockIdx.z;
  const int tx = threadIdx.x, ty = threadIdx.y;
  if (z == 4) {
    const int i = (blockIdx.y * 32 + blockIdx.x) * 256 + ty * 32 + tx;  // 0..262143
    const float4* p = (const float4*)x + (size_t)i * 4;
    float4 v0 = p[0], v1 = p[1], v2 = p[2], v3 = p[3];
    half8 h0 = {(f16)v0.x, (f16)v0.y, (f16)v0.z, (f16)v0.w,
                (f16)v1.x, (f16)v1.y, (f16)v1.z, (f16)v1.w};
    half8 h1 = {(f16)v2.x, (f16)v2.y, (f16)v2.z, (f16)v2.w,
                (f16)v3.x, (f16)v3.y, (f16)v3.z, (f16)v3.w};
    *(half8*)(xh + (size_t)i * 16) = h0;
    *(half8*)(xh + (size_t)i * 16 + 8) = h1;
    return;
  }
  __shared__ float tile[32][33];
  const float* W = (z == 0) ? Wq : (z == 1) ? Wk : (z == 2) ? Wv : Wo;
  f16* out = wt + (size_t)z * DIM * DIM;
  const int x0 = blockIdx.x * 32, y0 = blockIdx.y * 32;
#pragma unroll
  for (int i = 0; i < 4; ++i)
    tile[ty + i * 8][tx] = W[(size_t)(y0 + ty + i * 8) * DIM + (x0 + tx)];
  __syncthreads();
#pragma unroll
  for (int i = 0; i < 4; ++i)
    out[(size_t)(x0 + ty + i * 8) * DIM + (y0 + tx)] = (f16)tile[tx][ty + i * 8];
}

// ---- V^T pre-transpose: vt[bh][d][n] = V[b][n][h*64+d] ----
__global__ __launch_bounds__(256) void k_vtrans(
    const f16* __restrict__ vh, f16* __restrict__ vt)
{
  __shared__ f16 T[64][72];
  const int tid = threadIdx.x;
  const int nt = blockIdx.x, bh = blockIdx.y;
  const int b = bh >> 4, h = bh & 15;
  const int n0 = nt * 64;
  const f16* src = vh + (size_t)b * SEQ * DIM + (size_t)h * DH;
#pragma unroll
  for (int i = 0; i < 2; ++i) {
    const int n = (tid >> 3) + i * 32;
    const int cc = tid & 7;
    half8 v = *(const half8*)(src + (size_t)(n0 + n) * DIM + cc * 8);
#pragma unroll
    for (int j = 0; j < 8; ++j) T[cc * 8 + j][n] = v[j];
  }
  __syncthreads();
  f16* dst = vt + (size_t)bh * DH * SEQ;
#pragma unroll
  for (int i = 0; i < 2; ++i) {
    const int d = (tid >> 3) + i * 32;
    const int cc = tid & 7;
    half8 w = *(const half8*)&T[d][cc * 8];
    *(half8*)(dst + (size_t)d * SEQ + n0 + cc * 8) = w;
  }
}

// ---- fp16 GEMM, 128x128 tile, BK=32, gll double-buffer, 1 barrier/step ----
template <bool OUT_F32>
__global__ __launch_bounds__(256) void k_gemm2(
    const f16* __restrict__ A, const f16* __restrict__ BT,
    void* __restrict__ Cptr, const float* __restrict__ bias,
    int M, int N, int K, size_t bt_zstride, size_t c_zstride)
{
  __shared__ f16 SB[2][8192];

  const int tid = threadIdx.x;
  const int lane = tid & 63;
  const int wid = tid >> 6;
  const int wr = (wid >> 1) * 64, wc = (wid & 1) * 64;
  const int li = lane & 15, lg = lane >> 4;

  const f16* BTz = BT + (size_t)blockIdx.z * bt_zstride;
  const int row0 = blockIdx.x * 128, col0 = blockIdx.y * 128;

  const int c0 = tid;
  const int c1 = 256 + tid;
  const f16* a0 = A + (size_t)(row0 + (c0 >> 2)) * K + (c0 & 3) * 8;
  const f16* a1 = A + (size_t)(row0 + (c1 >> 2)) * K + (c1 & 3) * 8;
  const f16* b0 = BTz + (size_t)(col0 + (c0 >> 2)) * K + (c0 & 3) * 8;
  const f16* b1 = BTz + (size_t)(col0 + (c1 >> 2)) * K + (c1 & 3) * 8;
  const int da0 = wid * 512, da1 = 2048 + wid * 512;

  const floatx4 zero4 = {0.f, 0.f, 0.f, 0.f};
  floatx4 acc[4][4];
#pragma unroll
  for (int m = 0; m < 4; ++m)
#pragma unroll
    for (int n = 0; n < 4; ++n) acc[m][n] = zero4;

  auto issue = [&](int buf) {
    gll16(a0, &SB[buf][da0]);
    gll16(a1, &SB[buf][da1]);
    gll16(b0, &SB[buf][4096 + da0]);
    gll16(b1, &SB[buf][4096 + da1]);
    a0 += 32; a1 += 32; b0 += 32; b1 += 32;
  };

  const int nstep = K >> 5;
  issue(0);

  auto step = [&](int buf, int t) {
    asm volatile("s_waitcnt vmcnt(0)" ::: "memory");
    __builtin_amdgcn_s_barrier();
    asm volatile("" ::: "memory");
    if (t + 1 < nstep) issue(buf ^ 1);
    const f16* As = &SB[buf][0];
    const f16* Bs = &SB[buf][4096];
    half8 af[4], bf[4];
#pragma unroll
    for (int m = 0; m < 4; ++m)
      af[m] = *(const half8*)&As[(wr + m * 16 + li) * 32 + lg * 8];
#pragma unroll
    for (int n = 0; n < 4; ++n)
      bf[n] = *(const half8*)&Bs[(wc + n * 16 + li) * 32 + lg * 8];
#pragma unroll
    for (int m = 0; m < 4; ++m)
#pragma unroll
      for (int n = 0; n < 4; ++n)
        acc[m][n] = __builtin_amdgcn_mfma_f32_16x16x32_f16(af[m], bf[n], acc[m][n], 0, 0, 0);
  };

  for (int t2 = 0; t2 < nstep; t2 += 2) {
    step(0, t2);
    step(1, t2 + 1);
  }

#pragma unroll
  for (int m = 0; m < 4; ++m)
#pragma unroll
    for (int n = 0; n < 4; ++n)
#pragma unroll
      for (int r = 0; r < 4; ++r) {
        const int row = row0 + wr + m * 16 + lg * 4 + r;
        const int col = col0 + wc + n * 16 + li;
        if constexpr (OUT_F32) {
          float* C = (float*)Cptr + (size_t)blockIdx.z * c_zstride;
          C[(size_t)row * N + col] = acc[m][n][r] + bias[col];
        } else {
          f16* C = (f16*)Cptr + (size_t)blockIdx.z * c_zstride;
          C[(size_t)row * N + col] = (f16)acc[m][n][r];
        }
      }
}

// ---- out-proj GEMM: 128x64 tile (512 blocks -> 2+ blocks/CU), fp32 out + bias ----
__global__ __launch_bounds__(256) void k_gemm3(
    const f16* __restrict__ A, const f16* __restrict__ BT,
    float* __restrict__ C, const float* __restrict__ bias)
{
  __shared__ f16 SB[2][6144];  // A 4096 f16 | B 2048 f16

  const int tid = threadIdx.x;
  const int lane = tid & 63;
  const int wid = tid >> 6;
  const int wr = (wid >> 1) * 64, wc = (wid & 1) * 32;
  const int li = lane & 15, lg = lane >> 4;

  const int row0 = blockIdx.x * 128, col0 = blockIdx.y * 64;

  const int c0 = tid, c1 = tid + 256;
  const f16* a0 = A + (size_t)(row0 + (c0 >> 2)) * DIM + (c0 & 3) * 8;
  const f16* a1 = A + (size_t)(row0 + (c1 >> 2)) * DIM + (c1 & 3) * 8;
  const f16* b0 = BT + (size_t)(col0 + (tid >> 2)) * DIM + (tid & 3) * 8;

  const floatx4 zero4 = {0.f, 0.f, 0.f, 0.f};
  floatx4 acc[4][2];
#pragma unroll
  for (int m = 0; m < 4; ++m)
#pragma unroll
    for (int n = 0; n < 2; ++n) acc[m][n] = zero4;

  auto issue = [&](int buf) {
    f16* B = &SB[buf][0];
    gll16(a0, B + tid * 8);
    gll16(a1, B + 2048 + tid * 8);
    gll16(b0, B + 4096 + tid * 8);
    a0 += 32; a1 += 32; b0 += 32;
  };

  issue(0);

  auto step = [&](int buf, int t) {
    asm volatile("s_waitcnt vmcnt(0)" ::: "memory");
    __builtin_amdgcn_s_barrier();
    asm volatile("" ::: "memory");
    if (t + 1 < 32) issue(buf ^ 1);
    const f16* As = &SB[buf][0];
    const f16* Bs = &SB[buf][4096];
    half8 af[4], bf[2];
#pragma unroll
    for (int m = 0; m < 4; ++m)
      af[m] = *(const half8*)&As[(wr + m * 16 + li) * 32 + lg * 8];
#pragma unroll
    for (int n = 0; n < 2; ++n)
      bf[n] = *(const half8*)&Bs[(wc + n * 16 + li) * 32 + lg * 8];
#pragma unroll
    for (int m = 0; m < 4; ++m)
#pragma unroll
      for (int n = 0; n < 2; ++n)
        acc[m][n] = __builtin_amdgcn_mfma_f32_16x16x32_f16(af[m], bf[n], acc[m][n], 0, 0, 0);
  };

  for (int t2 = 0; t2 < 32; t2 += 2) {
    step(0, t2);
    step(1, t2 + 1);
  }

#pragma unroll
  for (int m = 0; m < 4; ++m)
#pragma unroll
    for (int n = 0; n < 2; ++n)
#pragma unroll
      for (int r = 0; r < 4; ++r) {
        const int row = row0 + wr + m * 16 + lg * 4 + r;
        const int col = col0 + wc + n * 16 + li;
        C[(size_t)row * DIM + col] = acc[m][n][r] + bias[col];
      }
}

// ---- flash attention v8: r5's attn4 + deferred lsum combine (one end-of-loop shfl) ----
__global__ __launch_bounds__(512) void k_attn8(
    const f16* __restrict__ qh, const f16* __restrict__ kh,
    const f16* __restrict__ vt, f16* __restrict__ oh)
{
  __shared__ f16 KV[2][16384];   // [buf][K0|V0|K1|V1] 4096 f16 each, 16B-col swizzled
  __shared__ float bc[8][32];
  __shared__ float Lm[4][32], Ll[4][32], W0[4][32], W1[4][32];

  const int tid = threadIdx.x;
  const int lane = tid & 63;
  const int wid = tid >> 6;   // 0..7
  const int g = wid >> 2;     // kv-half group
  const int sub = wid & 3;    // q-subtile
  const int col = lane & 31;
  const int hi = lane >> 5;

  const int id = blockIdx.x;
  const int xcd = id & 7;
  const int j = id >> 3;
  const int bh = xcd * 4 + (j >> 4);
  const int qi = j & 15;
  const int b = bh >> 4, h = bh & 15;

  const int q0 = qi * 128 + sub * 32;
  const size_t xbase = (size_t)b * SEQ * DIM + (size_t)h * DH;
  const size_t vtbase = (size_t)bh * DH * SEQ;

  const float SC = 0.125f * 1.44269504089f;  // scale * log2(e)
  const float RTRAW = 8.0f / SC;

  const int lc = tid & 511;
  const int srow = lc >> 3;
  const int sw = ((lc & 7) ^ (srow & 7)) * 8;
  const f16* ks0 = kh + xbase + (size_t)srow * DIM + sw;
  const f16* ks1 = kh + xbase + (size_t)(1024 + srow) * DIM + sw;
  const f16* vs0 = vt + vtbase + (size_t)srow * SEQ + sw;
  const f16* vs1 = vt + vtbase + (size_t)srow * SEQ + 1024 + sw;

  auto issue = [&](int buf) {
    f16* B = &KV[buf][wid * 512];
    gll16(ks0, B);
    gll16(vs0, B + 4096);
    gll16(ks1, B + 8192);
    gll16(vs1, B + 12288);
    ks0 += 64 * DIM; ks1 += 64 * DIM; vs0 += 64; vs1 += 64;
  };

  half8 qb[4];
  {
    const f16* qrow = qh + xbase + (size_t)(q0 + col) * DIM;
#pragma unroll
    for (int s = 0; s < 4; ++s) qb[s] = *(const half8*)(qrow + s * 16 + hi * 8);
  }

  f32x16 o0 = {0, 0, 0, 0, 0, 0, 0, 0, 0, 0, 0, 0, 0, 0, 0, 0};
  f32x16 o1 = {0, 0, 0, 0, 0, 0, 0, 0, 0, 0, 0, 0, 0, 0, 0, 0};
  float m = -1e30f, lsum = 0.f;  // lsum: per-lane half-row partial

  issue(0);

  auto tile = [&](int buf, int t) {
    asm volatile("s_waitcnt vmcnt(0)" ::: "memory");
    __builtin_amdgcn_s_barrier();
    asm volatile("" ::: "memory");
    if (t < 15) issue(buf ^ 1);
    const f16* Ks = &KV[buf][g * 8192];
    const f16* Vs = Ks + 4096;

#pragma unroll
    for (int kvs = 0; kvs < 2; ++kvs) {
      const int krow = kvs * 32 + col;
      f32x16 sacc = {0, 0, 0, 0, 0, 0, 0, 0, 0, 0, 0, 0, 0, 0, 0, 0};
      __builtin_amdgcn_s_setprio(1);
#pragma unroll
      for (int s = 0; s < 4; ++s) {
        const int cc = (2 * s + hi) ^ (krow & 7);
        half8 ka = *(const half8*)&Ks[krow * 64 + cc * 8];
        sacc = __builtin_amdgcn_mfma_f32_32x32x16_f16(ka, qb[s], sacc, 0, 0, 0);
      }
      __builtin_amdgcn_s_setprio(0);

      // tree row-max
      float x0 = fmaxf(fmaxf(sacc[0], sacc[1]), fmaxf(sacc[2], sacc[3]));
      float x1 = fmaxf(fmaxf(sacc[4], sacc[5]), fmaxf(sacc[6], sacc[7]));
      float x2 = fmaxf(fmaxf(sacc[8], sacc[9]), fmaxf(sacc[10], sacc[11]));
      float x3 = fmaxf(fmaxf(sacc[12], sacc[13]), fmaxf(sacc[14], sacc[15]));
      float smax = fmaxf(fmaxf(x0, x1), fmaxf(x2, x3));
      smax = fmaxf(smax, __shfl_xor(smax, 32));

      if (!__all(smax <= m + RTRAW)) {
        const float mn = fmaxf(m, smax);
        const float alpha = fexp2((m - mn) * SC);  // same across the hi-pair
        m = mn;
        lsum *= alpha;
        if (hi == 0) bc[wid][col] = alpha;
#pragma unroll
        for (int r = 0; r < 16; ++r) {
          const float a2 = bc[wid][(r & 3) + 8 * (r >> 2) + 4 * hi];
          o0[r] *= a2;
          o1[r] *= a2;
        }
      }

      const float mc = m * SC;
      float pw[16];
#pragma unroll
      for (int r = 0; r < 16; ++r) pw[r] = fexp2(fmaf(sacc[r], SC, -mc));
      float s0 = (pw[0] + pw[1]) + (pw[2] + pw[3]);
      float s1 = (pw[4] + pw[5]) + (pw[6] + pw[7]);
      float s2 = (pw[8] + pw[9]) + (pw[10] + pw[11]);
      float s3 = (pw[12] + pw[13]) + (pw[14] + pw[15]);
      lsum += (s0 + s1) + (s2 + s3);  // deferred: no in-loop cross-lane combine

      __builtin_amdgcn_s_setprio(1);
#pragma unroll
      for (int s2i = 0; s2i < 2; ++s2i) {
        const int rb = s2i * 8;
        unsigned X0 = pkrtz(pw[rb + 0], pw[rb + 1]);
        unsigned X1 = pkrtz(pw[rb + 2], pw[rb + 3]);
        unsigned Y0 = pkrtz(pw[rb + 4], pw[rb + 5]);
        unsigned Y1 = pkrtz(pw[rb + 6], pw[rb + 7]);
        pl32swap(X0, Y0);
        pl32swap(X1, Y1);
        const half8 paf = __builtin_bit_cast(half8, (uint4v){X0, X1, Y0, Y1});
        const int kc = kvs * 4 + s2i * 2 + hi;
#pragma unroll
        for (int dt = 0; dt < 2; ++dt) {
          const int vrow = dt * 32 + col;
          const int cc = kc ^ (vrow & 7);
          half8 vb = *(const half8*)&Vs[vrow * 64 + cc * 8];
          if (dt == 0)
            o0 = __builtin_amdgcn_mfma_f32_32x32x16_f16(paf, vb, o0, 0, 0, 0);
          else
            o1 = __builtin_amdgcn_mfma_f32_32x32x16_f16(paf, vb, o1, 0, 0, 0);
        }
      }
      __builtin_amdgcn_s_setprio(0);
    }
  };

  for (int t2 = 0; t2 < 16; t2 += 2) {
    tile(0, t2);
    tile(1, t2 + 1);
  }

  lsum += __shfl_xor(lsum, 32);  // full row-sum for q = col

  // ---- merge the two kv-half partials via LDS ----
  if (g == 1) {
    const float inv = 1.0f / lsum;
    if (hi == 0) { Lm[sub][col] = m; Ll[sub][col] = lsum; bc[wid][col] = inv; }
    f16* po = &KV[0][0] + sub * 2048;  // 32 rows x 64 cols fp16, normalized
#pragma unroll
    for (int r = 0; r < 16; ++r) {
      const int qr = (r & 3) + 8 * (r >> 2) + 4 * hi;
      const float iv = bc[wid][qr];
      po[qr * 64 + col] = (f16)(o0[r] * iv);
      po[qr * 64 + 32 + col] = (f16)(o1[r] * iv);
    }
  }
  __syncthreads();
  if (g == 0) {
    const float m1 = Lm[sub][col], l1 = Ll[sub][col];
    const float M = fmaxf(m, m1);
    const float e0 = fexp2((m - M) * SC);
    const float a0 = lsum * e0;
    const float a1 = l1 * fexp2((m1 - M) * SC);
    const float rden = 1.0f / (a0 + a1);
    const float c0 = e0 * rden;
    const float w1 = a1 * rden;
    if (hi == 0) { W0[sub][col] = c0; W1[sub][col] = w1; }
    const f16* po = &KV[0][0] + sub * 2048;
#pragma unroll
    for (int r = 0; r < 16; ++r) {
      const int qr = (r & 3) + 8 * (r >> 2) + 4 * hi;
      const float c0r = W0[sub][qr], w1r = W1[sub][qr];
      f16* orow = oh + xbase + (size_t)(q0 + qr) * DIM;
      orow[col] = (f16)(c0r * o0[r] + w1r * (float)po[qr * 64 + col]);
      orow[32 + col] = (f16)(c0r * o1[r] + w1r * (float)po[qr * 64 + 32 + col]);
    }
  }
}

extern "C" void kernel_launch(void* const* d_in, const int* in_sizes, int n_in,
                              void* d_out, int out_size, void* d_ws, size_t ws_size,
                              hipStream_t stream)
{
  const float* x  = (const float*)d_in[0];
  const float* Wq = (const float*)d_in[1];
  const float* Wk = (const float*)d_in[2];
  const float* Wv = (const float*)d_in[3];
  const float* Wo = (const float*)d_in[4];
  const float* bo = (const float*)d_in[5];

  char* ws = (char*)d_ws;
  f16* wt   = (f16*)ws;                               // 8 MB
  f16* qkvh = (f16*)(ws + (size_t)8 * 1024 * 1024);   // 24 MB
  f16* ohp  = (f16*)(ws + (size_t)32 * 1024 * 1024);  // 8 MB (aliases xh)
  f16* vtb  = (f16*)(ws + (size_t)40 * 1024 * 1024);  // 8 MB
  f16* xh   = ohp;  // x-fp16 consumed by QKV GEMM before attn writes ohp

  k_prep<<<dim3(32, 32, 5), dim3(32, 8), 0, stream>>>(Wq, Wk, Wv, Wo, x, wt, xh);

  k_gemm2<false><<<dim3(32, 8, 3), 256, 0, stream>>>(
      xh, wt, qkvh, nullptr, MTOT, DIM, DIM,
      (size_t)DIM * DIM, (size_t)MTOT * DIM);

  k_vtrans<<<dim3(32, 32), 256, 0, stream>>>(
      qkvh + (size_t)2 * MTOT * DIM, vtb);

  k_attn8<<<512, 512, 0, stream>>>(
      qkvh, qkvh + (size_t)MTOT * DIM, vtb, ohp);

  k_gemm3<<<dim3(32, 16), 256, 0, stream>>>(
      ohp, wt + (size_t)3 * DIM * DIM, (float*)d_out, bo);
}